// Round 2
// baseline (272.256 us; speedup 1.0000x reference)
//
#include <hip/hip_runtime.h>
#include <cstdint>
#include <cstddef>

typedef unsigned short u16;
typedef unsigned int u32;
typedef u16 u16x4 __attribute__((ext_vector_type(4)));
typedef u16 u16x8 __attribute__((ext_vector_type(8)));
typedef __bf16 bf16x8 __attribute__((ext_vector_type(8)));
typedef float f32x4 __attribute__((ext_vector_type(4)));

#define B_   2
#define N_   2048
#define F_   512
#define D_   512
#define W_   128
#define E3   1536   /* 3*D */
#define MTOT 4096   /* B*N */

/* ---------------- QKV GEMM: qkv[m][e] = sum_k x[m][k] * W[e][k] ----------------
 * bf16 hi/lo split (3 MFMA passes, lo*lo dropped) for fp32-grade accuracy on the
 * 2% absmax budget. 128x128 tile, BK=32, 4 waves of 64x64, 16x16x32 MFMA. */
#define TM 128
#define TE 128
#define BK 32
#define LDK 40  /* padded k-stride in u16 (80 B rows: 16B-aligned, conflict-light) */

__device__ __forceinline__ u16 bf_hi(float f) {
  u32 u = __float_as_uint(f);
  return (u16)((u + 0x7fffu + ((u >> 16) & 1u)) >> 16); /* RNE truncate to bf16 */
}
__device__ __forceinline__ float bf_f(u16 h) { return __uint_as_float(((u32)h) << 16); }

__device__ __forceinline__ void cvt4(const float4 v, u16x4& h, u16x4& l) {
  h.x = bf_hi(v.x); l.x = bf_hi(v.x - bf_f(h.x));
  h.y = bf_hi(v.y); l.y = bf_hi(v.y - bf_f(h.y));
  h.z = bf_hi(v.z); l.z = bf_hi(v.z - bf_f(h.z));
  h.w = bf_hi(v.w); l.w = bf_hi(v.w - bf_f(h.w));
}

__device__ __forceinline__ f32x4 mfma_bf16(u16x8 a, u16x8 b, f32x4 c) {
  return __builtin_amdgcn_mfma_f32_16x16x32_bf16(
      __builtin_bit_cast(bf16x8, a), __builtin_bit_cast(bf16x8, b), c, 0, 0, 0);
}

__global__ __launch_bounds__(256) void qkv_gemm(const float* __restrict__ X,
                                                const float* __restrict__ Wl,
                                                float* __restrict__ QKV) {
  __shared__ __align__(16) u16 AsH[TM * LDK];
  __shared__ __align__(16) u16 AsL[TM * LDK];
  __shared__ __align__(16) u16 BsH[TE * LDK];
  __shared__ __align__(16) u16 BsL[TE * LDK];

  const int tid = threadIdx.x;
  const int m0 = blockIdx.x * TM;
  const int e0 = blockIdx.y * TE;
  const int lane = tid & 63;
  const int wave = tid >> 6;
  const int wm = (wave >> 1) * 64;   /* wave's M offset in tile */
  const int we = (wave & 1) * 64;    /* wave's E offset in tile */
  const int qd = lane >> 4;          /* quad 0..3 */
  const int l16 = lane & 15;

  /* staging: thread -> (row = tid>>1, 16 consecutive k at (tid&1)*16) */
  const int srow = tid >> 1;
  const int skoff = (tid & 1) * 16;

  f32x4 acc[4][4];
#pragma unroll
  for (int i = 0; i < 4; ++i)
#pragma unroll
    for (int j = 0; j < 4; ++j) acc[i][j] = (f32x4){0.f, 0.f, 0.f, 0.f};

  const float* ag = X + (size_t)(m0 + srow) * F_ + skoff;
  const float* bg = Wl + (size_t)(e0 + srow) * F_ + skoff;
  u16* aHp = &AsH[srow * LDK + skoff];
  u16* aLp = &AsL[srow * LDK + skoff];
  u16* bHp = &BsH[srow * LDK + skoff];
  u16* bLp = &BsL[srow * LDK + skoff];

  for (int k0 = 0; k0 < F_; k0 += BK) {
#pragma unroll
    for (int i = 0; i < 4; ++i) {
      float4 av = *(const float4*)(ag + k0 + 4 * i);
      float4 bv = *(const float4*)(bg + k0 + 4 * i);
      u16x4 h, l;
      cvt4(av, h, l);
      *(u16x4*)(aHp + 4 * i) = h;
      *(u16x4*)(aLp + 4 * i) = l;
      cvt4(bv, h, l);
      *(u16x4*)(bHp + 4 * i) = h;
      *(u16x4*)(bLp + 4 * i) = l;
    }
    __syncthreads();

    u16x8 fAH[4], fAL[4], fBH[4], fBL[4];
#pragma unroll
    for (int mi = 0; mi < 4; ++mi) {
      int r = wm + mi * 16 + l16;
      fAH[mi] = *(const u16x8*)&AsH[r * LDK + qd * 8];
      fAL[mi] = *(const u16x8*)&AsL[r * LDK + qd * 8];
    }
#pragma unroll
    for (int ei = 0; ei < 4; ++ei) {
      int r = we + ei * 16 + l16;
      fBH[ei] = *(const u16x8*)&BsH[r * LDK + qd * 8];
      fBL[ei] = *(const u16x8*)&BsL[r * LDK + qd * 8];
    }
#pragma unroll
    for (int mi = 0; mi < 4; ++mi)
#pragma unroll
      for (int ei = 0; ei < 4; ++ei) {
        acc[mi][ei] = mfma_bf16(fAH[mi], fBH[ei], acc[mi][ei]);
        acc[mi][ei] = mfma_bf16(fAH[mi], fBL[ei], acc[mi][ei]);
        acc[mi][ei] = mfma_bf16(fAL[mi], fBH[ei], acc[mi][ei]);
      }
    __syncthreads();
  }

  /* C/D layout: row = qd*4 + reg, col = lane&15 (verified mapping) */
#pragma unroll
  for (int mi = 0; mi < 4; ++mi)
#pragma unroll
    for (int ei = 0; ei < 4; ++ei)
#pragma unroll
      for (int r = 0; r < 4; ++r) {
        int row = m0 + wm + mi * 16 + qd * 4 + r;
        int col = e0 + we + ei * 16 + l16;
        QKV[(size_t)row * E3 + col] = acc[mi][ei][r];
      }
}

/* ---------------- Sliding-window attention, query-tiled ----------------
 * One block per TQ=16 consecutive queries of one batch. Window union =
 * W-1+TQ = 143 K/V rows -> ~14x less cache traffic than 1-query blocks.
 * Padded positions (r<0) have logit 0.0 and v=0; they DO participate in
 * the softmax denominator (logit 0 -> exp(0-m) term), matching the
 * reference's zero-padding. */
#define TQ 16
#define UJ (W_ - 1 + TQ) /* 143 union rows; loop padded to 144 */

__global__ __launch_bounds__(512) void attn_kernel(const float* __restrict__ QKV,
                                                   float* __restrict__ Out) {
  const int m0 = blockIdx.x * TQ;   /* global query row of tile start */
  const int b = m0 >> 11;
  const int n0 = m0 & 2047;         /* within-batch index */
  const int t = threadIdx.x;        /* 0..511 */

  __shared__ float att[TQ][W_];     /* 8 KB */

  /* ---- logits: group g = t>>3 (64 groups of 8 lanes). qi = g&15 fixed
   * per group; jq = g>>4 in [0,4) -> j = j0 + jq. Lane covers float4
   * chunks sub+8m of D=512. Q held in registers (16 float4). ---- */
  const int sub = t & 7;
  const int g = t >> 3;
  const int qi = g & 15;
  const int jq = g >> 4;

  float4 qreg[16];
  {
    const float4* qrow = (const float4*)(QKV + (size_t)(m0 + qi) * E3);
#pragma unroll
    for (int m = 0; m < 16; ++m) qreg[m] = qrow[sub + 8 * m];
  }

  const float* kbase = QKV + (size_t)(b * N_) * E3 + D_;
  for (int j0 = 0; j0 < 144; j0 += 4) {
    const int j = j0 + jq;
    const int w = j - qi;
    if (w >= 0 && w < W_) {
      const int r = n0 - (W_ - 1) + j;
      float p = 0.f;
      if (r >= 0) {
        const float4* kr = (const float4*)(kbase + (size_t)r * E3);
#pragma unroll
        for (int m = 0; m < 16; ++m) {
          float4 kv = kr[sub + 8 * m];
          float4 qv = qreg[m];
          p += kv.x * qv.x + kv.y * qv.y + kv.z * qv.z + kv.w * qv.w;
        }
      }
      p += __shfl_xor(p, 1);
      p += __shfl_xor(p, 2);
      p += __shfl_xor(p, 4);
      if (sub == 0) att[qi][w] = p;
    }
  }
  __syncthreads();

  /* ---- softmax: 16 threads per query row (within one wave; shfl masks
   * 1,2,4,8 stay in-group). Each thread owns 8 contiguous w. ---- */
  if (t < 256) {
    const int i = t >> 4;
    const int s16 = t & 15;
    float l[8];
    float mx = -1e30f;
#pragma unroll
    for (int r = 0; r < 8; ++r) {
      l[r] = att[i][s16 * 8 + r];
      mx = fmaxf(mx, l[r]);
    }
    mx = fmaxf(mx, __shfl_xor(mx, 1));
    mx = fmaxf(mx, __shfl_xor(mx, 2));
    mx = fmaxf(mx, __shfl_xor(mx, 4));
    mx = fmaxf(mx, __shfl_xor(mx, 8));
    float s = 0.f;
#pragma unroll
    for (int r = 0; r < 8; ++r) {
      l[r] = __expf(l[r] - mx);
      s += l[r];
    }
    s += __shfl_xor(s, 1);
    s += __shfl_xor(s, 2);
    s += __shfl_xor(s, 4);
    s += __shfl_xor(s, 8);
    const float inv = 1.f / s;
#pragma unroll
    for (int r = 0; r < 8; ++r) att[i][s16 * 8 + r] = l[r] * inv;
  }
  __syncthreads();

  /* ---- PV: thread (i2 = t>>7, d4 = t&127) accumulates 4 queries
   * i = i2*4+ii over union rows j; v row fetched once per j (all threads
   * at same j -> L1 broadcast); att reads are LDS broadcasts. ---- */
  const int d4 = t & 127;
  const int i2 = t >> 7;
  f32x4 acc[4];
#pragma unroll
  for (int ii = 0; ii < 4; ++ii) acc[ii] = (f32x4){0.f, 0.f, 0.f, 0.f};

  const float* vbase = QKV + (size_t)(b * N_) * E3 + 2 * D_;
  for (int j = 0; j < UJ; ++j) {
    const int r = n0 - (W_ - 1) + j;
    if (r < 0) continue; /* zero v rows contribute nothing */
    const float4 vv = ((const float4*)(vbase + (size_t)r * E3))[d4];
#pragma unroll
    for (int ii = 0; ii < 4; ++ii) {
      const int i = i2 * 4 + ii;
      const int w = j - i;
      if (w >= 0 && w < W_) {
        const float a = att[i][w];
        acc[ii].x += a * vv.x;
        acc[ii].y += a * vv.y;
        acc[ii].z += a * vv.z;
        acc[ii].w += a * vv.w;
      }
    }
  }
#pragma unroll
  for (int ii = 0; ii < 4; ++ii) {
    const int i = i2 * 4 + ii;
    float4 res = {acc[ii].x, acc[ii].y, acc[ii].z, acc[ii].w};
    ((float4*)(Out + (size_t)(m0 + i) * D_))[d4] = res;
  }
}

extern "C" void kernel_launch(void* const* d_in, const int* in_sizes, int n_in,
                              void* d_out, int out_size, void* d_ws, size_t ws_size,
                              hipStream_t stream) {
  const float* x = (const float*)d_in[0];    /* (B, N, F) fp32 */
  const float* wl = (const float*)d_in[1];   /* (3D, F) fp32 */
  float* out = (float*)d_out;                /* (B, N, D) fp32 */
  float* qkv = (float*)d_ws;                 /* (B*N, 3D) fp32 = 25.2 MB scratch */

  dim3 g1(MTOT / TM, E3 / TE); /* 32 x 12 */
  qkv_gemm<<<g1, 256, 0, stream>>>(x, wl, qkv);
  attn_kernel<<<MTOT / TQ, 512, 0, stream>>>(qkv, out);
}

// Round 3
// 124.221 us; speedup vs baseline: 2.1917x; 2.1917x over previous
//
#include <hip/hip_runtime.h>
#include <cstdint>
#include <cstddef>

typedef unsigned short u16;
typedef unsigned int u32;
typedef u16 u16x4 __attribute__((ext_vector_type(4)));
typedef u16 u16x8 __attribute__((ext_vector_type(8)));
typedef u32 u32x4 __attribute__((ext_vector_type(4)));
typedef __bf16 bf16x8 __attribute__((ext_vector_type(8)));
typedef float f32x4 __attribute__((ext_vector_type(4)));

#define B_   2
#define N_   2048
#define F_   512
#define D_   512
#define W_   128
#define E3   1536   /* 3*D */
#define MTOT 4096   /* B*N */
#define QK_ELEMS (MTOT * D_) /* 2,097,152 elements per plane */

/* ws layout (u16 planes of QK_ELEMS): Qh, Ql, Kh, Kl, Vt  (≈21 MB total) */

__device__ __forceinline__ u16 bf_hi(float f) {
  u32 u = __float_as_uint(f);
  return (u16)((u + 0x7fffu + ((u >> 16) & 1u)) >> 16); /* RNE to bf16 */
}
__device__ __forceinline__ float bf_f(u16 h) { return __uint_as_float(((u32)h) << 16); }

__device__ __forceinline__ void cvt4(const float4 v, u16x4& h, u16x4& l) {
  h.x = bf_hi(v.x); l.x = bf_hi(v.x - bf_f(h.x));
  h.y = bf_hi(v.y); l.y = bf_hi(v.y - bf_f(h.y));
  h.z = bf_hi(v.z); l.z = bf_hi(v.z - bf_f(h.z));
  h.w = bf_hi(v.w); l.w = bf_hi(v.w - bf_f(h.w));
}

__device__ __forceinline__ f32x4 mfma_bf16(u16x8 a, u16x8 b, f32x4 c) {
  return __builtin_amdgcn_mfma_f32_16x16x32_bf16(
      __builtin_bit_cast(bf16x8, a), __builtin_bit_cast(bf16x8, b), c, 0, 0, 0);
}

/* ---------------- QKV GEMM: qkv[m][e] = sum_k x[m][k] * W[e][k] ----------------
 * bf16 hi/lo split (3 MFMA passes). Epilogue writes MFMA-ready operands:
 *  - e in [0,512):    Qh/Ql bf16 row-major [4096][512]
 *  - e in [512,1024): Kh/Kl bf16 row-major [4096][512]
 *  - e in [1024,1536): Vt bf16-hi transposed [b][d 512][n 2048] (LDS transpose)
 */
#define TM 128
#define TE 128
#define BK 32
#define LDK 40

__global__ __launch_bounds__(256) void qkv_gemm(const float* __restrict__ X,
                                                const float* __restrict__ Wl,
                                                u16* __restrict__ Qh, u16* __restrict__ Ql,
                                                u16* __restrict__ Kh, u16* __restrict__ Kl,
                                                u16* __restrict__ Vt) {
  __shared__ __align__(16) u16 smem[4 * TM * LDK]; /* 40960 B */
  u16* AsH = smem;
  u16* AsL = smem + TM * LDK;
  u16* BsH = smem + 2 * TM * LDK;
  u16* BsL = smem + 3 * TM * LDK;

  const int tid = threadIdx.x;
  const int m0 = blockIdx.x * TM;
  const int e0 = blockIdx.y * TE;
  const int lane = tid & 63;
  const int wave = tid >> 6;
  const int wm = (wave >> 1) * 64;
  const int we = (wave & 1) * 64;
  const int qd = lane >> 4;
  const int l16 = lane & 15;

  const int srow = tid >> 1;
  const int skoff = (tid & 1) * 16;

  f32x4 acc[4][4];
#pragma unroll
  for (int i = 0; i < 4; ++i)
#pragma unroll
    for (int j = 0; j < 4; ++j) acc[i][j] = (f32x4){0.f, 0.f, 0.f, 0.f};

  const float* ag = X + (size_t)(m0 + srow) * F_ + skoff;
  const float* bg = Wl + (size_t)(e0 + srow) * F_ + skoff;
  u16* aHp = &AsH[srow * LDK + skoff];
  u16* aLp = &AsL[srow * LDK + skoff];
  u16* bHp = &BsH[srow * LDK + skoff];
  u16* bLp = &BsL[srow * LDK + skoff];

  for (int k0 = 0; k0 < F_; k0 += BK) {
#pragma unroll
    for (int i = 0; i < 4; ++i) {
      float4 av = *(const float4*)(ag + k0 + 4 * i);
      float4 bv = *(const float4*)(bg + k0 + 4 * i);
      u16x4 h, l;
      cvt4(av, h, l);
      *(u16x4*)(aHp + 4 * i) = h;
      *(u16x4*)(aLp + 4 * i) = l;
      cvt4(bv, h, l);
      *(u16x4*)(bHp + 4 * i) = h;
      *(u16x4*)(bLp + 4 * i) = l;
    }
    __syncthreads();

    u16x8 fAH[4], fAL[4], fBH[4], fBL[4];
#pragma unroll
    for (int mi = 0; mi < 4; ++mi) {
      int r = wm + mi * 16 + l16;
      fAH[mi] = *(const u16x8*)&AsH[r * LDK + qd * 8];
      fAL[mi] = *(const u16x8*)&AsL[r * LDK + qd * 8];
    }
#pragma unroll
    for (int ei = 0; ei < 4; ++ei) {
      int r = we + ei * 16 + l16;
      fBH[ei] = *(const u16x8*)&BsH[r * LDK + qd * 8];
      fBL[ei] = *(const u16x8*)&BsL[r * LDK + qd * 8];
    }
#pragma unroll
    for (int mi = 0; mi < 4; ++mi)
#pragma unroll
      for (int ei = 0; ei < 4; ++ei) {
        acc[mi][ei] = mfma_bf16(fAH[mi], fBH[ei], acc[mi][ei]);
        acc[mi][ei] = mfma_bf16(fAH[mi], fBL[ei], acc[mi][ei]);
        acc[mi][ei] = mfma_bf16(fAL[mi], fBH[ei], acc[mi][ei]);
      }
    __syncthreads();
  }

  /* C/D layout: row = qd*4 + reg, col = lane&15 */
  const int third = e0 >> 9; /* 0=Q, 1=K, 2=V */
  if (third < 2) {
    u16* H = third ? Kh : Qh;
    u16* L = third ? Kl : Ql;
    const int ecol0 = (e0 & 511) + we;
#pragma unroll
    for (int mi = 0; mi < 4; ++mi)
#pragma unroll
      for (int ei = 0; ei < 4; ++ei)
#pragma unroll
        for (int r = 0; r < 4; ++r) {
          int row = m0 + wm + mi * 16 + qd * 4 + r;
          int col = ecol0 + ei * 16 + l16;
          float v = acc[mi][ei][r];
          u16 h = bf_hi(v);
          H[(size_t)row * D_ + col] = h;
          L[(size_t)row * D_ + col] = bf_hi(v - bf_f(h));
        }
  } else {
    /* V: per-wave 64x64 LDS transpose (stride 66 u16), then coalesced Vt write.
     * Main loop's trailing __syncthreads already fenced smem reuse; the
     * transpose buffer is wave-private so no further barrier is needed. */
    u16* vbuf = smem + wave * 4224; /* [64][66] u16 */
#pragma unroll
    for (int mi = 0; mi < 4; ++mi)
#pragma unroll
      for (int ei = 0; ei < 4; ++ei)
#pragma unroll
        for (int r2 = 0; r2 < 2; ++r2) {
          int e_in = ei * 16 + l16;
          int m_in = mi * 16 + qd * 4 + r2 * 2;
          u32 p = (u32)bf_hi(acc[mi][ei][r2 * 2]) |
                  ((u32)bf_hi(acc[mi][ei][r2 * 2 + 1]) << 16);
          *(u32*)&vbuf[e_in * 66 + m_in] = p;
        }
    __builtin_amdgcn_s_waitcnt(0); /* drain lgkm before wave-local readback */
    const int dbase = (e0 - 1024) + we;
    const int mb = (m0 & 2047) + wm;
    const int bb = m0 >> 11;
    u16* vt = Vt + (size_t)bb * (D_ * N_);
#pragma unroll
    for (int it = 0; it < 4; ++it) {
      int e_in = it * 16 + (lane >> 2);
      int mc = lane & 3;
      u32 q0[8];
#pragma unroll
      for (int c4 = 0; c4 < 8; ++c4)
        q0[c4] = *(const u32*)&vbuf[e_in * 66 + mc * 16 + c4 * 2];
      u16* gp = vt + (size_t)(dbase + e_in) * N_ + mb + mc * 16;
      *(u32x4*)gp = (u32x4){q0[0], q0[1], q0[2], q0[3]};
      *(u32x4*)(gp + 8) = (u32x4){q0[4], q0[5], q0[6], q0[7]};
    }
  }
}

/* ---------------- MFMA sliding-window attention ----------------
 * Block = 16 queries (m0), 4 waves, 256 threads, grid 256.
 * Slot j in [0,192): K/V row r = n0 - 128 + j. Query i attends j in
 * [i+1, i+128] (w = j-i-1). r<0 slots: logit forced to 0.0 (they're in the
 * softmax denominator, matching the reference zero-pad) but P=0 so the
 * (clamped, garbage) V rows contribute nothing. */
#define TQA 16
#define NSL 192
#define SA 200  /* att stride (f32) */
#define SP 208  /* pS stride (u16), 416 B: 16B-aligned rows */

__global__ __launch_bounds__(256) void attn_kernel(const u16* __restrict__ Qh,
                                                   const u16* __restrict__ Ql,
                                                   const u16* __restrict__ Kh,
                                                   const u16* __restrict__ Kl,
                                                   const u16* __restrict__ Vt,
                                                   float* __restrict__ Out) {
  const int m0 = blockIdx.x * TQA;
  const int b = m0 >> 11;
  const int n0 = m0 & 2047;
  const int t = threadIdx.x;
  const int lane = t & 63;
  const int w = t >> 6;
  const int qd = lane >> 4;
  const int l16 = lane & 15;

  __shared__ __align__(16) float att[TQA][SA]; /* 12.8 KB */
  __shared__ __align__(16) u16 pS[TQA][SP];    /* 6.7 KB */

  /* ---- Phase 1: logits = Q K^T, 3-pass hi/lo. Wave w owns j-tiles 3w..3w+2. */
  f32x4 acc[3];
#pragma unroll
  for (int nt = 0; nt < 3; ++nt) acc[nt] = (f32x4){0.f, 0.f, 0.f, 0.f};

  const size_t qrow = (size_t)(m0 + l16) * D_ + qd * 8;
  for (int ks = 0; ks < 16; ++ks) {
    u16x8 qh = *(const u16x8*)(Qh + qrow + ks * 32);
    u16x8 ql = *(const u16x8*)(Ql + qrow + ks * 32);
#pragma unroll
    for (int nt = 0; nt < 3; ++nt) {
      int j = (w * 3 + nt) * 16 + l16;
      int rl = n0 - 128 + j;
      int rg = b * N_ + (rl > 0 ? rl : 0);
      const size_t koff = (size_t)rg * D_ + ks * 32 + qd * 8;
      u16x8 kh = *(const u16x8*)(Kh + koff);
      u16x8 kl = *(const u16x8*)(Kl + koff);
      acc[nt] = mfma_bf16(qh, kh, acc[nt]);
      acc[nt] = mfma_bf16(qh, kl, acc[nt]);
      acc[nt] = mfma_bf16(ql, kh, acc[nt]);
    }
  }
#pragma unroll
  for (int nt = 0; nt < 3; ++nt)
#pragma unroll
    for (int r = 0; r < 4; ++r)
      att[qd * 4 + r][(w * 3 + nt) * 16 + l16] = acc[nt][r];
  __syncthreads();

  /* ---- Phase 2: softmax per query row i over j in [i+1, i+128]. 16 threads
   * per row (contiguous in-wave); each owns 12 slots. */
  {
    const int i = t >> 4;
    const int c = t & 15;
    float ev[12];
    float mx = -1e30f;
#pragma unroll
    for (int s = 0; s < 12; ++s) {
      int j = c * 12 + s;
      bool inw = (j >= i + 1) && (j <= i + 128);
      float v = -1e30f;
      if (inw) v = (n0 - 128 + j < 0) ? 0.f : att[i][j];
      ev[s] = v;
      mx = fmaxf(mx, v);
    }
    mx = fmaxf(mx, __shfl_xor(mx, 1));
    mx = fmaxf(mx, __shfl_xor(mx, 2));
    mx = fmaxf(mx, __shfl_xor(mx, 4));
    mx = fmaxf(mx, __shfl_xor(mx, 8));
    float sum = 0.f;
#pragma unroll
    for (int s = 0; s < 12; ++s) {
      ev[s] = (ev[s] > -1e29f) ? __expf(ev[s] - mx) : 0.f;
      sum += ev[s];
    }
    sum += __shfl_xor(sum, 1);
    sum += __shfl_xor(sum, 2);
    sum += __shfl_xor(sum, 4);
    sum += __shfl_xor(sum, 8);
    const float inv = 1.f / sum;
#pragma unroll
    for (int s = 0; s < 12; ++s) {
      int j = c * 12 + s;
      bool zv = (n0 - 128 + j) < 0; /* zero-padded rows: in denom, P=0 */
      pS[i][j] = bf_hi(zv ? 0.f : ev[s] * inv);
    }
  }
  __syncthreads();

  /* ---- Phase 3: Out = P V. Wave w owns d-range [w*128, w*128+128).
   * V frags contiguous from Vt (window dim fast, 16B-aligned: r0 mod 8 == 0). */
  f32x4 oacc[8];
#pragma unroll
  for (int nt = 0; nt < 8; ++nt) oacc[nt] = (f32x4){0.f, 0.f, 0.f, 0.f};

  const u16* vtb = Vt + (size_t)b * (D_ * N_);
  for (int kk = 0; kk < 6; ++kk) {
    u16x8 pa = *(const u16x8*)&pS[l16][kk * 32 + qd * 8];
    const int rl = n0 - 128 + kk * 32 + qd * 8; /* may be <0: P=0 guards */
#pragma unroll
    for (int nt = 0; nt < 8; ++nt) {
      int d = w * 128 + nt * 16 + l16;
      u16x8 vv = *(const u16x8*)(vtb + (size_t)d * N_ + rl);
      oacc[nt] = mfma_bf16(pa, vv, oacc[nt]);
    }
  }
#pragma unroll
  for (int nt = 0; nt < 8; ++nt)
#pragma unroll
    for (int r = 0; r < 4; ++r)
      Out[(size_t)(m0 + qd * 4 + r) * D_ + w * 128 + nt * 16 + l16] = oacc[nt][r];
}

extern "C" void kernel_launch(void* const* d_in, const int* in_sizes, int n_in,
                              void* d_out, int out_size, void* d_ws, size_t ws_size,
                              hipStream_t stream) {
  const float* x = (const float*)d_in[0];
  const float* wl = (const float*)d_in[1];
  float* out = (float*)d_out;

  u16* Qh = (u16*)d_ws;
  u16* Ql = Qh + QK_ELEMS;
  u16* Kh = Ql + QK_ELEMS;
  u16* Kl = Kh + QK_ELEMS;
  u16* Vt = Kl + QK_ELEMS;

  dim3 g1(MTOT / TM, E3 / TE); /* 32 x 12 */
  qkv_gemm<<<g1, 256, 0, stream>>>(x, wl, Qh, Ql, Kh, Kl, Vt);
  attn_kernel<<<MTOT / TQA, 256, 0, stream>>>(Qh, Ql, Kh, Kl, Vt, out);
}

// Round 4
// 119.398 us; speedup vs baseline: 2.2802x; 1.0404x over previous
//
#include <hip/hip_runtime.h>
#include <cstdint>
#include <cstddef>

typedef unsigned short u16;
typedef unsigned int u32;
typedef u16 u16x4 __attribute__((ext_vector_type(4)));
typedef u16 u16x8 __attribute__((ext_vector_type(8)));
typedef u32 u32x4 __attribute__((ext_vector_type(4)));
typedef __bf16 bf16x8 __attribute__((ext_vector_type(8)));
typedef float f32x4 __attribute__((ext_vector_type(4)));

#define B_   2
#define N_   2048
#define F_   512
#define D_   512
#define W_   128
#define E3   1536
#define MTOT 4096
#define XELEMS (MTOT * F_)   /* 2,097,152 */
#define WELEMS (E3 * F_)     /* 786,432 */
#define QK_ELEMS (MTOT * D_) /* 2,097,152 */

__device__ __forceinline__ u16 bf_hi(float f) {
  u32 u = __float_as_uint(f);
  return (u16)((u + 0x7fffu + ((u >> 16) & 1u)) >> 16); /* RNE to bf16 */
}
__device__ __forceinline__ float bf_f(u16 h) { return __uint_as_float(((u32)h) << 16); }

__device__ __forceinline__ void cvt4(const float4 v, u16x4& h, u16x4& l) {
  h.x = bf_hi(v.x); l.x = bf_hi(v.x - bf_f(h.x));
  h.y = bf_hi(v.y); l.y = bf_hi(v.y - bf_f(h.y));
  h.z = bf_hi(v.z); l.z = bf_hi(v.z - bf_f(h.z));
  h.w = bf_hi(v.w); l.w = bf_hi(v.w - bf_f(h.w));
}

__device__ __forceinline__ f32x4 mfma_bf16(u16x8 a, u16x8 b, f32x4 c) {
  return __builtin_amdgcn_mfma_f32_16x16x32_bf16(
      __builtin_bit_cast(bf16x8, a), __builtin_bit_cast(bf16x8, b), c, 0, 0, 0);
}

__device__ __forceinline__ void glds16(const u16* g, u16* l) {
  __builtin_amdgcn_global_load_lds(
      (const __attribute__((address_space(1))) void*)g,
      (__attribute__((address_space(3))) void*)l, 16, 0, 0);
}

/* ---------------- Prepass: fp32 -> bf16 hi/lo planes for X and W ----------- */
__global__ __launch_bounds__(256) void cvt_hilo(const float* __restrict__ X,
                                                const float* __restrict__ Wl,
                                                u16* __restrict__ Xh, u16* __restrict__ Xl,
                                                u16* __restrict__ Wh, u16* __restrict__ Wlo) {
  const int i = blockIdx.x * 256 + threadIdx.x; /* one float4 per thread */
  const int n4X = XELEMS / 4;
  u16x4 h, l;
  if (i < n4X) {
    float4 v = ((const float4*)X)[i];
    cvt4(v, h, l);
    ((u16x4*)Xh)[i] = h;
    ((u16x4*)Xl)[i] = l;
  } else {
    int j = i - n4X;
    float4 v = ((const float4*)Wl)[j];
    cvt4(v, h, l);
    ((u16x4*)Wh)[j] = h;
    ((u16x4*)Wlo)[j] = l;
  }
}

/* ---------------- QKV GEMM (m97 structure): qkv[m][e] = sum_k x[m][k]*W[e][k]
 * Pure-bf16 hot loop: global_load_lds(16B) staging of pre-converted hi/lo
 * planes, ds_read_b128 fragments, 3-pass hi/lo MFMA (lo*lo dropped).
 * Epilogue: Q/K -> hi/lo bf16 row-major; V -> bf16-hi transposed [b][d][n]. */
#define TM 128
#define TE 128
#define BK 32

__global__ __launch_bounds__(256) void qkv_gemm(const u16* __restrict__ Xh,
                                                const u16* __restrict__ Xl,
                                                const u16* __restrict__ Wh,
                                                const u16* __restrict__ Wlo,
                                                u16* __restrict__ Qh, u16* __restrict__ Ql,
                                                u16* __restrict__ Kh, u16* __restrict__ Kl,
                                                u16* __restrict__ Vt) {
  __shared__ __align__(16) u16 smem[16896]; /* 33792 B: staging 32 KB / vbuf 33 KB */
  u16* sAh = smem;
  u16* sAl = smem + 4096;
  u16* sBh = smem + 8192;
  u16* sBl = smem + 12288; /* each [128][32] u16, rows 64 B, NO padding (glds) */

  const int tid = threadIdx.x;
  const int m0 = blockIdx.x * TM;
  const int e0 = blockIdx.y * TE;
  const int lane = tid & 63;
  const int wave = tid >> 6;
  const int wm = (wave >> 1) * 64;
  const int we = (wave & 1) * 64;
  const int qd = lane >> 4;
  const int l16 = lane & 15;

  /* glds lane map: lane i -> lds byte base+16i == row (i>>2), kchunk (i&3)*8 */
  const int lrow = lane >> 2;
  const int lkc = (lane & 3) * 8;

  f32x4 acc[4][4];
#pragma unroll
  for (int i = 0; i < 4; ++i)
#pragma unroll
    for (int j = 0; j < 4; ++j) acc[i][j] = (f32x4){0.f, 0.f, 0.f, 0.f};

  /* wave w stages rows [w*32, w*32+32) of each plane (2 issues of 16 rows) */
  const int r0 = wave * 32;
  const size_t ga0 = (size_t)(m0 + r0 + lrow) * F_ + lkc;
  const size_t ga1 = (size_t)(m0 + r0 + 16 + lrow) * F_ + lkc;
  const size_t gb0 = (size_t)(e0 + r0 + lrow) * F_ + lkc;
  const size_t gb1 = (size_t)(e0 + r0 + 16 + lrow) * F_ + lkc;
  u16* lA0 = sAh + r0 * 32;        /* +lane*16B implied by HW */
  u16* lA1 = sAh + (r0 + 16) * 32;
  const int PL = 4096; /* plane stride in u16 */

  for (int k0 = 0; k0 < F_; k0 += BK) {
    glds16(Xh + ga0 + k0, lA0);
    glds16(Xh + ga1 + k0, lA1);
    glds16(Xl + ga0 + k0, lA0 + PL);
    glds16(Xl + ga1 + k0, lA1 + PL);
    glds16(Wh + gb0 + k0, lA0 + 2 * PL);
    glds16(Wh + gb1 + k0, lA1 + 2 * PL);
    glds16(Wlo + gb0 + k0, lA0 + 3 * PL);
    glds16(Wlo + gb1 + k0, lA1 + 3 * PL);
    __syncthreads();

    u16x8 fAH[4], fAL[4], fBH[4], fBL[4];
#pragma unroll
    for (int mi = 0; mi < 4; ++mi) {
      int r = wm + mi * 16 + l16;
      fAH[mi] = *(const u16x8*)&sAh[r * 32 + qd * 8];
      fAL[mi] = *(const u16x8*)&sAl[r * 32 + qd * 8];
    }
#pragma unroll
    for (int ei = 0; ei < 4; ++ei) {
      int r = we + ei * 16 + l16;
      fBH[ei] = *(const u16x8*)&sBh[r * 32 + qd * 8];
      fBL[ei] = *(const u16x8*)&sBl[r * 32 + qd * 8];
    }
#pragma unroll
    for (int mi = 0; mi < 4; ++mi)
#pragma unroll
      for (int ei = 0; ei < 4; ++ei) {
        acc[mi][ei] = mfma_bf16(fAH[mi], fBH[ei], acc[mi][ei]);
        acc[mi][ei] = mfma_bf16(fAH[mi], fBL[ei], acc[mi][ei]);
        acc[mi][ei] = mfma_bf16(fAL[mi], fBH[ei], acc[mi][ei]);
      }
    __syncthreads();
  }

  /* C/D layout: row = qd*4 + reg, col = lane&15 */
  const int third = e0 >> 9; /* 0=Q, 1=K, 2=V */
  if (third < 2) {
    u16* H = third ? Kh : Qh;
    u16* L = third ? Kl : Ql;
    const int ecol0 = (e0 & 511) + we;
#pragma unroll
    for (int mi = 0; mi < 4; ++mi)
#pragma unroll
      for (int ei = 0; ei < 4; ++ei)
#pragma unroll
        for (int r = 0; r < 4; ++r) {
          int row = m0 + wm + mi * 16 + qd * 4 + r;
          int col = ecol0 + ei * 16 + l16;
          float v = acc[mi][ei][r];
          u16 h = bf_hi(v);
          H[(size_t)row * D_ + col] = h;
          L[(size_t)row * D_ + col] = bf_hi(v - bf_f(h));
        }
  } else {
    /* V: per-wave 64x64 LDS transpose (stride 66 u16), coalesced Vt write.
     * Trailing __syncthreads of the K-loop fences staging reuse; vbuf is
     * wave-private. */
    u16* vbuf = smem + wave * 4224; /* [64][66] u16 */
#pragma unroll
    for (int mi = 0; mi < 4; ++mi)
#pragma unroll
      for (int ei = 0; ei < 4; ++ei)
#pragma unroll
        for (int r2 = 0; r2 < 2; ++r2) {
          int e_in = ei * 16 + l16;
          int m_in = mi * 16 + qd * 4 + r2 * 2;
          u32 p = (u32)bf_hi(acc[mi][ei][r2 * 2]) |
                  ((u32)bf_hi(acc[mi][ei][r2 * 2 + 1]) << 16);
          *(u32*)&vbuf[e_in * 66 + m_in] = p;
        }
    __builtin_amdgcn_s_waitcnt(0); /* drain lgkm before wave-local readback */
    const int dbase = (e0 - 1024) + we;
    const int mb = (m0 & 2047) + wm;
    const int bb = m0 >> 11;
    u16* vt = Vt + (size_t)bb * (D_ * N_);
#pragma unroll
    for (int it = 0; it < 4; ++it) {
      int e_in = it * 16 + (lane >> 2);
      int mc = lane & 3;
      u32 q0[8];
#pragma unroll
      for (int c4 = 0; c4 < 8; ++c4)
        q0[c4] = *(const u32*)&vbuf[e_in * 66 + mc * 16 + c4 * 2];
      u16* gp = vt + (size_t)(dbase + e_in) * N_ + mb + mc * 16;
      *(u32x4*)gp = (u32x4){q0[0], q0[1], q0[2], q0[3]};
      *(u32x4*)(gp + 8) = (u32x4){q0[4], q0[5], q0[6], q0[7]};
    }
  }
}

/* ---------------- MFMA sliding-window attention (unchanged from R2) -------- */
#define TQA 16
#define SA 200
#define SP 208

__global__ __launch_bounds__(256) void attn_kernel(const u16* __restrict__ Qh,
                                                   const u16* __restrict__ Ql,
                                                   const u16* __restrict__ Kh,
                                                   const u16* __restrict__ Kl,
                                                   const u16* __restrict__ Vt,
                                                   float* __restrict__ Out) {
  const int m0 = blockIdx.x * TQA;
  const int b = m0 >> 11;
  const int n0 = m0 & 2047;
  const int t = threadIdx.x;
  const int lane = t & 63;
  const int w = t >> 6;
  const int qd = lane >> 4;
  const int l16 = lane & 15;

  __shared__ __align__(16) float att[TQA][SA];
  __shared__ __align__(16) u16 pS[TQA][SP];

  /* Phase 1: logits = Q K^T, 3-pass hi/lo. Wave w owns j-tiles 3w..3w+2. */
  f32x4 acc[3];
#pragma unroll
  for (int nt = 0; nt < 3; ++nt) acc[nt] = (f32x4){0.f, 0.f, 0.f, 0.f};

  const size_t qrow = (size_t)(m0 + l16) * D_ + qd * 8;
  for (int ks = 0; ks < 16; ++ks) {
    u16x8 qh = *(const u16x8*)(Qh + qrow + ks * 32);
    u16x8 ql = *(const u16x8*)(Ql + qrow + ks * 32);
#pragma unroll
    for (int nt = 0; nt < 3; ++nt) {
      int j = (w * 3 + nt) * 16 + l16;
      int rl = n0 - 128 + j;
      int rg = b * N_ + (rl > 0 ? rl : 0);
      const size_t koff = (size_t)rg * D_ + ks * 32 + qd * 8;
      u16x8 kh = *(const u16x8*)(Kh + koff);
      u16x8 kl = *(const u16x8*)(Kl + koff);
      acc[nt] = mfma_bf16(qh, kh, acc[nt]);
      acc[nt] = mfma_bf16(qh, kl, acc[nt]);
      acc[nt] = mfma_bf16(ql, kh, acc[nt]);
    }
  }
#pragma unroll
  for (int nt = 0; nt < 3; ++nt)
#pragma unroll
    for (int r = 0; r < 4; ++r)
      att[qd * 4 + r][(w * 3 + nt) * 16 + l16] = acc[nt][r];
  __syncthreads();

  /* Phase 2: softmax per query i over j in [i+1, i+128]; zero-pad rows keep
   * logit 0.0 in the denominator, P forced to 0. */
  {
    const int i = t >> 4;
    const int c = t & 15;
    float ev[12];
    float mx = -1e30f;
#pragma unroll
    for (int s = 0; s < 12; ++s) {
      int j = c * 12 + s;
      bool inw = (j >= i + 1) && (j <= i + 128);
      float v = -1e30f;
      if (inw) v = (n0 - 128 + j < 0) ? 0.f : att[i][j];
      ev[s] = v;
      mx = fmaxf(mx, v);
    }
    mx = fmaxf(mx, __shfl_xor(mx, 1));
    mx = fmaxf(mx, __shfl_xor(mx, 2));
    mx = fmaxf(mx, __shfl_xor(mx, 4));
    mx = fmaxf(mx, __shfl_xor(mx, 8));
    float sum = 0.f;
#pragma unroll
    for (int s = 0; s < 12; ++s) {
      ev[s] = (ev[s] > -1e29f) ? __expf(ev[s] - mx) : 0.f;
      sum += ev[s];
    }
    sum += __shfl_xor(sum, 1);
    sum += __shfl_xor(sum, 2);
    sum += __shfl_xor(sum, 4);
    sum += __shfl_xor(sum, 8);
    const float inv = 1.f / sum;
#pragma unroll
    for (int s = 0; s < 12; ++s) {
      int j = c * 12 + s;
      bool zv = (n0 - 128 + j) < 0;
      pS[i][j] = bf_hi(zv ? 0.f : ev[s] * inv);
    }
  }
  __syncthreads();

  /* Phase 3: Out = P V, V contiguous from Vt (window fast axis). */
  f32x4 oacc[8];
#pragma unroll
  for (int nt = 0; nt < 8; ++nt) oacc[nt] = (f32x4){0.f, 0.f, 0.f, 0.f};

  const u16* vtb = Vt + (size_t)b * (D_ * N_);
  for (int kk = 0; kk < 6; ++kk) {
    u16x8 pa = *(const u16x8*)&pS[l16][kk * 32 + qd * 8];
    const int rl = n0 - 128 + kk * 32 + qd * 8;
#pragma unroll
    for (int nt = 0; nt < 8; ++nt) {
      int d = w * 128 + nt * 16 + l16;
      u16x8 vv = *(const u16x8*)(vtb + (size_t)d * N_ + rl);
      oacc[nt] = mfma_bf16(pa, vv, oacc[nt]);
    }
  }
#pragma unroll
  for (int nt = 0; nt < 8; ++nt)
#pragma unroll
    for (int r = 0; r < 4; ++r)
      Out[(size_t)(m0 + qd * 4 + r) * D_ + w * 128 + nt * 16 + l16] = oacc[nt][r];
}

extern "C" void kernel_launch(void* const* d_in, const int* in_sizes, int n_in,
                              void* d_out, int out_size, void* d_ws, size_t ws_size,
                              hipStream_t stream) {
  const float* x = (const float*)d_in[0];
  const float* wl = (const float*)d_in[1];
  float* out = (float*)d_out;

  u16* Xh = (u16*)d_ws;
  u16* Xl = Xh + XELEMS;
  u16* Wh = Xl + XELEMS;
  u16* Wlo = Wh + WELEMS;
  u16* Qh = Wlo + WELEMS;
  u16* Ql = Qh + QK_ELEMS;
  u16* Kh = Ql + QK_ELEMS;
  u16* Kl = Kh + QK_ELEMS;
  u16* Vt = Kl + QK_ELEMS;

  cvt_hilo<<<(XELEMS + WELEMS) / 4 / 256, 256, 0, stream>>>(x, wl, Xh, Xl, Wh, Wlo);
  dim3 g1(MTOT / TM, E3 / TE); /* 32 x 12 */
  qkv_gemm<<<g1, 256, 0, stream>>>(Xh, Xl, Wh, Wlo, Qh, Ql, Kh, Kl, Vt);
  attn_kernel<<<MTOT / TQA, 256, 0, stream>>>(Qh, Ql, Kh, Kl, Vt, out);
}

// Round 5
// 118.511 us; speedup vs baseline: 2.2973x; 1.0075x over previous
//
#include <hip/hip_runtime.h>
#include <cstdint>
#include <cstddef>

typedef unsigned short u16;
typedef unsigned int u32;
typedef u16 u16x4 __attribute__((ext_vector_type(4)));
typedef u16 u16x8 __attribute__((ext_vector_type(8)));
typedef u32 u32x4 __attribute__((ext_vector_type(4)));
typedef __bf16 bf16x8 __attribute__((ext_vector_type(8)));
typedef float f32x4 __attribute__((ext_vector_type(4)));

#define B_   2
#define N_   2048
#define F_   512
#define D_   512
#define W_   128
#define E3   1536
#define MTOT 4096
#define XELEMS (MTOT * F_)
#define WELEMS (E3 * F_)
#define QK_ELEMS (MTOT * D_)

__device__ __forceinline__ u16 bf_hi(float f) {
  u32 u = __float_as_uint(f);
  return (u16)((u + 0x7fffu + ((u >> 16) & 1u)) >> 16); /* RNE to bf16 */
}
__device__ __forceinline__ float bf_f(u16 h) { return __uint_as_float(((u32)h) << 16); }

__device__ __forceinline__ void cvt4(const float4 v, u16x4& h, u16x4& l) {
  h.x = bf_hi(v.x); l.x = bf_hi(v.x - bf_f(h.x));
  h.y = bf_hi(v.y); l.y = bf_hi(v.y - bf_f(h.y));
  h.z = bf_hi(v.z); l.z = bf_hi(v.z - bf_f(h.z));
  h.w = bf_hi(v.w); l.w = bf_hi(v.w - bf_f(h.w));
}

__device__ __forceinline__ f32x4 mfma_bf16(u16x8 a, u16x8 b, f32x4 c) {
  return __builtin_amdgcn_mfma_f32_16x16x32_bf16(
      __builtin_bit_cast(bf16x8, a), __builtin_bit_cast(bf16x8, b), c, 0, 0, 0);
}

__device__ __forceinline__ void glds16(const u16* g, u16* l) {
  __builtin_amdgcn_global_load_lds(
      (const __attribute__((address_space(1))) void*)g,
      (__attribute__((address_space(3))) void*)l, 16, 0, 0);
}

/* ---------------- Prepass: fp32 -> bf16 hi/lo planes for X and W ----------- */
__global__ __launch_bounds__(256) void cvt_hilo(const float* __restrict__ X,
                                                const float* __restrict__ Wl,
                                                u16* __restrict__ Xh, u16* __restrict__ Xl,
                                                u16* __restrict__ Wh, u16* __restrict__ Wlo) {
  const int i = blockIdx.x * 256 + threadIdx.x;
  const int n4X = XELEMS / 4;
  u16x4 h, l;
  if (i < n4X) {
    float4 v = ((const float4*)X)[i];
    cvt4(v, h, l);
    ((u16x4*)Xh)[i] = h;
    ((u16x4*)Xl)[i] = l;
  } else {
    int j = i - n4X;
    float4 v = ((const float4*)Wl)[j];
    cvt4(v, h, l);
    ((u16x4*)Wh)[j] = h;
    ((u16x4*)Wlo)[j] = l;
  }
}

/* ---------------- QKV GEMM (m97 structure + XOR-swizzled LDS) --------------
 * glds writes lane i at base+16i (fixed), so instead of padding we swizzle
 * WHICH global chunk each lane fetches: lane i holds chunk (i&3)^((lrow>>1)&3)
 * of row lrow. Reader: frag (r, qd) at byte r*64 + (qd^((l16>>1)&3))*16 ->
 * 16 lanes spread exactly 2 per bank-quad = conflict-free (2-way is free). */
#define TM 128
#define TE 128
#define BK 32

__global__ __launch_bounds__(256) void qkv_gemm(const u16* __restrict__ Xh,
                                                const u16* __restrict__ Xl,
                                                const u16* __restrict__ Wh,
                                                const u16* __restrict__ Wlo,
                                                u16* __restrict__ Qh, u16* __restrict__ Ql,
                                                u16* __restrict__ Kh, u16* __restrict__ Kl,
                                                u16* __restrict__ Vt) {
  __shared__ __align__(16) u16 smem[16896]; /* 33792 B */
  u16* sAh = smem;
  u16* sAl = smem + 4096;
  u16* sBh = smem + 8192;
  u16* sBl = smem + 12288; /* each [128][32] u16, rows 64 B, chunk-swizzled */

  const int tid = threadIdx.x;
  const int m0 = blockIdx.x * TM;
  const int e0 = blockIdx.y * TE;
  const int lane = tid & 63;
  const int wave = tid >> 6;
  const int wm = (wave >> 1) * 64;
  const int we = (wave & 1) * 64;
  const int qd = lane >> 4;
  const int l16 = lane & 15;

  /* glds lane map: lane -> row lrow, fetches swizzled chunk cg */
  const int lrow = lane >> 2;
  const int cg = (lane & 3) ^ ((lrow >> 1) & 3);
  const int lkc = cg * 8; /* u16 offset of fetched chunk */

  f32x4 acc[4][4];
#pragma unroll
  for (int i = 0; i < 4; ++i)
#pragma unroll
    for (int j = 0; j < 4; ++j) acc[i][j] = (f32x4){0.f, 0.f, 0.f, 0.f};

  const int r0 = wave * 32;
  const size_t ga0 = (size_t)(m0 + r0 + lrow) * F_ + lkc;
  const size_t ga1 = (size_t)(m0 + r0 + 16 + lrow) * F_ + lkc;
  const size_t gb0 = (size_t)(e0 + r0 + lrow) * F_ + lkc;
  const size_t gb1 = (size_t)(e0 + r0 + 16 + lrow) * F_ + lkc;
  u16* lA0 = sAh + r0 * 32;
  u16* lA1 = sAh + (r0 + 16) * 32;
  const int PL = 4096;

  /* reader swizzle: uniform per lane (wm/we/mi*16 are multiples of 16) */
  const int swz = (l16 >> 1) & 3;
  const int rdoff = (qd ^ swz) * 8; /* u16 offset within row */

  for (int k0 = 0; k0 < F_; k0 += BK) {
    glds16(Xh + ga0 + k0, lA0);
    glds16(Xh + ga1 + k0, lA1);
    glds16(Xl + ga0 + k0, lA0 + PL);
    glds16(Xl + ga1 + k0, lA1 + PL);
    glds16(Wh + gb0 + k0, lA0 + 2 * PL);
    glds16(Wh + gb1 + k0, lA1 + 2 * PL);
    glds16(Wlo + gb0 + k0, lA0 + 3 * PL);
    glds16(Wlo + gb1 + k0, lA1 + 3 * PL);
    __syncthreads();

    u16x8 fAH[4], fAL[4], fBH[4], fBL[4];
#pragma unroll
    for (int mi = 0; mi < 4; ++mi) {
      int r = wm + mi * 16 + l16;
      fAH[mi] = *(const u16x8*)&sAh[r * 32 + rdoff];
      fAL[mi] = *(const u16x8*)&sAl[r * 32 + rdoff];
    }
#pragma unroll
    for (int ei = 0; ei < 4; ++ei) {
      int r = we + ei * 16 + l16;
      fBH[ei] = *(const u16x8*)&sBh[r * 32 + rdoff];
      fBL[ei] = *(const u16x8*)&sBl[r * 32 + rdoff];
    }
#pragma unroll
    for (int mi = 0; mi < 4; ++mi)
#pragma unroll
      for (int ei = 0; ei < 4; ++ei) {
        acc[mi][ei] = mfma_bf16(fAH[mi], fBH[ei], acc[mi][ei]);
        acc[mi][ei] = mfma_bf16(fAH[mi], fBL[ei], acc[mi][ei]);
        acc[mi][ei] = mfma_bf16(fAL[mi], fBH[ei], acc[mi][ei]);
      }
    __syncthreads();
  }

  /* C/D layout: row = qd*4 + reg, col = lane&15 */
  const int third = e0 >> 9;
  if (third < 2) {
    u16* H = third ? Kh : Qh;
    u16* L = third ? Kl : Ql;
    const int ecol0 = (e0 & 511) + we;
#pragma unroll
    for (int mi = 0; mi < 4; ++mi)
#pragma unroll
      for (int ei = 0; ei < 4; ++ei)
#pragma unroll
        for (int r = 0; r < 4; ++r) {
          int row = m0 + wm + mi * 16 + qd * 4 + r;
          int col = ecol0 + ei * 16 + l16;
          float v = acc[mi][ei][r];
          u16 h = bf_hi(v);
          H[(size_t)row * D_ + col] = h;
          L[(size_t)row * D_ + col] = bf_hi(v - bf_f(h));
        }
  } else {
    /* V: per-wave 64x64 LDS transpose (stride 66 u16), coalesced Vt write. */
    u16* vbuf = smem + wave * 4224;
#pragma unroll
    for (int mi = 0; mi < 4; ++mi)
#pragma unroll
      for (int ei = 0; ei < 4; ++ei)
#pragma unroll
        for (int r2 = 0; r2 < 2; ++r2) {
          int e_in = ei * 16 + l16;
          int m_in = mi * 16 + qd * 4 + r2 * 2;
          u32 p = (u32)bf_hi(acc[mi][ei][r2 * 2]) |
                  ((u32)bf_hi(acc[mi][ei][r2 * 2 + 1]) << 16);
          *(u32*)&vbuf[e_in * 66 + m_in] = p;
        }
    __builtin_amdgcn_s_waitcnt(0);
    const int dbase = (e0 - 1024) + we;
    const int mb = (m0 & 2047) + wm;
    const int bb = m0 >> 11;
    u16* vt = Vt + (size_t)bb * (D_ * N_);
#pragma unroll
    for (int it = 0; it < 4; ++it) {
      int e_in = it * 16 + (lane >> 2);
      int mc = lane & 3;
      u32 q0[8];
#pragma unroll
      for (int c4 = 0; c4 < 8; ++c4)
        q0[c4] = *(const u32*)&vbuf[e_in * 66 + mc * 16 + c4 * 2];
      u16* gp = vt + (size_t)(dbase + e_in) * N_ + mb + mc * 16;
      *(u32x4*)gp = (u32x4){q0[0], q0[1], q0[2], q0[3]};
      *(u32x4*)(gp + 8) = (u32x4){q0[4], q0[5], q0[6], q0[7]};
    }
  }
}

/* ---------------- MFMA sliding-window attention, 8 waves + split-K ---------
 * 512 threads. Phase 1: wave = (jw = w&3 -> 3 j-tiles, kh = w>>2 -> half of
 * the D reduction); halves summed in softmax. Phase 3: wave w owns 64 d-cols.
 * 2 waves/SIMD for latency overlap (R4's 1 wave/SIMD was latency-exposed). */
#define TQA 16
#define SA 200
#define SP 208

__global__ __launch_bounds__(512) void attn_kernel(const u16* __restrict__ Qh,
                                                   const u16* __restrict__ Ql,
                                                   const u16* __restrict__ Kh,
                                                   const u16* __restrict__ Kl,
                                                   const u16* __restrict__ Vt,
                                                   float* __restrict__ Out) {
  const int m0 = blockIdx.x * TQA;
  const int b = m0 >> 11;
  const int n0 = m0 & 2047;
  const int t = threadIdx.x;
  const int lane = t & 63;
  const int w = t >> 6;
  const int qd = lane >> 4;
  const int l16 = lane & 15;

  __shared__ __align__(16) float att[2][TQA][SA]; /* 25.6 KB */
  __shared__ __align__(16) u16 pS[TQA][SP];       /* 6.7 KB */

  const int jw = w & 3;  /* j-tile group: tiles jw*3 .. jw*3+2 */
  const int kh = w >> 2; /* reduction half: ks in [kh*8, kh*8+8) */

  /* Phase 1: logits = Q K^T, 3-pass hi/lo, split-K across wave pairs. */
  f32x4 acc[3];
#pragma unroll
  for (int nt = 0; nt < 3; ++nt) acc[nt] = (f32x4){0.f, 0.f, 0.f, 0.f};

  const size_t qrow = (size_t)(m0 + l16) * D_ + qd * 8;
  for (int ks = kh * 8; ks < kh * 8 + 8; ++ks) {
    u16x8 qh = *(const u16x8*)(Qh + qrow + ks * 32);
    u16x8 ql = *(const u16x8*)(Ql + qrow + ks * 32);
#pragma unroll
    for (int nt = 0; nt < 3; ++nt) {
      int j = (jw * 3 + nt) * 16 + l16;
      int rl = n0 - 128 + j;
      int rg = b * N_ + (rl > 0 ? rl : 0);
      const size_t koff = (size_t)rg * D_ + ks * 32 + qd * 8;
      u16x8 kh8 = *(const u16x8*)(Kh + koff);
      u16x8 kl8 = *(const u16x8*)(Kl + koff);
      acc[nt] = mfma_bf16(qh, kh8, acc[nt]);
      acc[nt] = mfma_bf16(qh, kl8, acc[nt]);
      acc[nt] = mfma_bf16(ql, kh8, acc[nt]);
    }
  }
#pragma unroll
  for (int nt = 0; nt < 3; ++nt)
#pragma unroll
    for (int r = 0; r < 4; ++r)
      att[kh][qd * 4 + r][(jw * 3 + nt) * 16 + l16] = acc[nt][r];
  __syncthreads();

  /* Phase 2: softmax per query i over window; 32 threads/row, 6 slots each.
   * Zero-pad rows keep logit 0.0 in the denominator, P forced to 0. */
  {
    const int i = t >> 5;
    const int c = t & 31;
    float ev[6];
    float mx = -1e30f;
#pragma unroll
    for (int s = 0; s < 6; ++s) {
      int j = c * 6 + s;
      bool inw = (j >= i + 1) && (j <= i + 128);
      float v = -1e30f;
      if (inw) v = (n0 - 128 + j < 0) ? 0.f : att[0][i][j] + att[1][i][j];
      ev[s] = v;
      mx = fmaxf(mx, v);
    }
    mx = fmaxf(mx, __shfl_xor(mx, 1));
    mx = fmaxf(mx, __shfl_xor(mx, 2));
    mx = fmaxf(mx, __shfl_xor(mx, 4));
    mx = fmaxf(mx, __shfl_xor(mx, 8));
    mx = fmaxf(mx, __shfl_xor(mx, 16));
    float sum = 0.f;
#pragma unroll
    for (int s = 0; s < 6; ++s) {
      ev[s] = (ev[s] > -1e29f) ? __expf(ev[s] - mx) : 0.f;
      sum += ev[s];
    }
    sum += __shfl_xor(sum, 1);
    sum += __shfl_xor(sum, 2);
    sum += __shfl_xor(sum, 4);
    sum += __shfl_xor(sum, 8);
    sum += __shfl_xor(sum, 16);
    const float inv = 1.f / sum;
#pragma unroll
    for (int s = 0; s < 6; ++s) {
      int j = c * 6 + s;
      bool zv = (n0 - 128 + j) < 0;
      pS[i][j] = bf_hi(zv ? 0.f : ev[s] * inv);
    }
  }
  __syncthreads();

  /* Phase 3: Out = P V; wave w owns d-cols [w*64, w*64+64). */
  f32x4 oacc[4];
#pragma unroll
  for (int nt = 0; nt < 4; ++nt) oacc[nt] = (f32x4){0.f, 0.f, 0.f, 0.f};

  const u16* vtb = Vt + (size_t)b * (D_ * N_);
  for (int kk = 0; kk < 6; ++kk) {
    u16x8 pa = *(const u16x8*)&pS[l16][kk * 32 + qd * 8];
    const int rl = n0 - 128 + kk * 32 + qd * 8; /* may be <0: P=0 guards */
#pragma unroll
    for (int nt = 0; nt < 4; ++nt) {
      int d = w * 64 + nt * 16 + l16;
      u16x8 vv = *(const u16x8*)(vtb + (size_t)d * N_ + rl);
      oacc[nt] = mfma_bf16(pa, vv, oacc[nt]);
    }
  }
#pragma unroll
  for (int nt = 0; nt < 4; ++nt)
#pragma unroll
    for (int r = 0; r < 4; ++r)
      Out[(size_t)(m0 + qd * 4 + r) * D_ + w * 64 + nt * 16 + l16] = oacc[nt][r];
}

extern "C" void kernel_launch(void* const* d_in, const int* in_sizes, int n_in,
                              void* d_out, int out_size, void* d_ws, size_t ws_size,
                              hipStream_t stream) {
  const float* x = (const float*)d_in[0];
  const float* wl = (const float*)d_in[1];
  float* out = (float*)d_out;

  u16* Xh = (u16*)d_ws;
  u16* Xl = Xh + XELEMS;
  u16* Wh = Xl + XELEMS;
  u16* Wlo = Wh + WELEMS;
  u16* Qh = Wlo + WELEMS;
  u16* Ql = Qh + QK_ELEMS;
  u16* Kh = Ql + QK_ELEMS;
  u16* Kl = Kh + QK_ELEMS;
  u16* Vt = Kl + QK_ELEMS;

  cvt_hilo<<<(XELEMS + WELEMS) / 4 / 256, 256, 0, stream>>>(x, wl, Xh, Xl, Wh, Wlo);
  dim3 g1(MTOT / TM, E3 / TE);
  qkv_gemm<<<g1, 256, 0, stream>>>(Xh, Xl, Wh, Wlo, Qh, Ql, Kh, Kl, Vt);
  attn_kernel<<<MTOT / TQA, 512, 0, stream>>>(Qh, Ql, Kh, Kl, Vt, out);
}

// Round 6
// 96.564 us; speedup vs baseline: 2.8194x; 1.2273x over previous
//
#include <hip/hip_runtime.h>
#include <cstdint>
#include <cstddef>

typedef unsigned short u16;
typedef unsigned int u32;
typedef u16 u16x4 __attribute__((ext_vector_type(4)));
typedef u16 u16x8 __attribute__((ext_vector_type(8)));
typedef u32 u32x4 __attribute__((ext_vector_type(4)));
typedef _Float16 f16x8 __attribute__((ext_vector_type(8)));
typedef float f32x4 __attribute__((ext_vector_type(4)));

#define B_   2
#define N_   2048
#define F_   512
#define D_   512
#define W_   128
#define E3   1536
#define MTOT 4096
#define XELEMS (MTOT * F_)   /* 2,097,152 */
#define WELEMS (E3 * F_)     /* 786,432 */
#define QK_ELEMS (MTOT * D_) /* 2,097,152 */

__device__ __forceinline__ u16 f2h(float f) {
  return __builtin_bit_cast(u16, (_Float16)f); /* v_cvt_f16_f32, RNE */
}

__device__ __forceinline__ f32x4 mfma_f16(u16x8 a, u16x8 b, f32x4 c) {
  return __builtin_amdgcn_mfma_f32_16x16x32_f16(
      __builtin_bit_cast(f16x8, a), __builtin_bit_cast(f16x8, b), c, 0, 0, 0);
}

__device__ __forceinline__ void glds16(const u16* g, u16* l) {
  __builtin_amdgcn_global_load_lds(
      (const __attribute__((address_space(1))) void*)g,
      (__attribute__((address_space(3))) void*)l, 16, 0, 0);
}

/* ---------------- Prepass: fp32 -> fp16 planes for X and W ----------------
 * fp16 single-pass error budget: qkv err ~6e-4, out err ~5e-3 << 4.9e-2
 * threshold (and < the bf16-P/V-dominated 0.0156 of the hi/lo version). */
__global__ __launch_bounds__(256) void cvt_f16(const float* __restrict__ X,
                                               const float* __restrict__ Wl,
                                               u16* __restrict__ Xf, u16* __restrict__ Wf) {
  const int i = blockIdx.x * 256 + threadIdx.x; /* one float4 per thread */
  const int n4X = XELEMS / 4;
  u16x4 h;
  if (i < n4X) {
    float4 v = ((const float4*)X)[i];
    h.x = f2h(v.x); h.y = f2h(v.y); h.z = f2h(v.z); h.w = f2h(v.w);
    ((u16x4*)Xf)[i] = h;
  } else {
    int j = i - n4X;
    float4 v = ((const float4*)Wl)[j];
    h.x = f2h(v.x); h.y = f2h(v.y); h.z = f2h(v.z); h.w = f2h(v.w);
    ((u16x4*)Wf)[j] = h;
  }
}

/* ---------------- QKV GEMM, fp16 single-pass (m97 structure) ---------------
 * qkv[m][e] = sum_k x[m][k]*W[e][k]. 128x128 tile, BK=32, glds 16B staging,
 * XOR chunk swizzle (writer fetches chunk (i&3)^((lrow>>1)&3); reader offset
 * (qd^((l16>>1)&3))*16B) to spread ds_read_b128 across bank quads.
 * Epilogue: Q/K -> fp16 row-major planes; V -> fp16 transposed [b][d][n]. */
#define TM 128
#define TE 128
#define BK 32

__global__ __launch_bounds__(256) void qkv_gemm(const u16* __restrict__ Xf,
                                                const u16* __restrict__ Wf,
                                                u16* __restrict__ Qf,
                                                u16* __restrict__ Kf,
                                                u16* __restrict__ Vt) {
  __shared__ __align__(16) u16 smem[16896]; /* staging 16 KB; vbuf 33 KB */
  u16* sA = smem;
  u16* sB = smem + 4096; /* each [128][32] u16, rows 64 B, chunk-swizzled */

  const int tid = threadIdx.x;
  const int m0 = blockIdx.x * TM;
  const int e0 = blockIdx.y * TE;
  const int lane = tid & 63;
  const int wave = tid >> 6;
  const int wm = (wave >> 1) * 64;
  const int we = (wave & 1) * 64;
  const int qd = lane >> 4;
  const int l16 = lane & 15;

  const int lrow = lane >> 2;
  const int cg = (lane & 3) ^ ((lrow >> 1) & 3);
  const int lkc = cg * 8;

  f32x4 acc[4][4];
#pragma unroll
  for (int i = 0; i < 4; ++i)
#pragma unroll
    for (int j = 0; j < 4; ++j) acc[i][j] = (f32x4){0.f, 0.f, 0.f, 0.f};

  const int r0 = wave * 32;
  const size_t ga0 = (size_t)(m0 + r0 + lrow) * F_ + lkc;
  const size_t ga1 = (size_t)(m0 + r0 + 16 + lrow) * F_ + lkc;
  const size_t gb0 = (size_t)(e0 + r0 + lrow) * F_ + lkc;
  const size_t gb1 = (size_t)(e0 + r0 + 16 + lrow) * F_ + lkc;
  u16* lA0 = sA + r0 * 32;
  u16* lA1 = sA + (r0 + 16) * 32;
  u16* lB0 = sB + r0 * 32;
  u16* lB1 = sB + (r0 + 16) * 32;

  const int swz = (l16 >> 1) & 3;
  const int rdoff = (qd ^ swz) * 8;

  for (int k0 = 0; k0 < F_; k0 += BK) {
    glds16(Xf + ga0 + k0, lA0);
    glds16(Xf + ga1 + k0, lA1);
    glds16(Wf + gb0 + k0, lB0);
    glds16(Wf + gb1 + k0, lB1);
    __syncthreads();

    u16x8 fA[4], fB[4];
#pragma unroll
    for (int mi = 0; mi < 4; ++mi)
      fA[mi] = *(const u16x8*)&sA[(wm + mi * 16 + l16) * 32 + rdoff];
#pragma unroll
    for (int ei = 0; ei < 4; ++ei)
      fB[ei] = *(const u16x8*)&sB[(we + ei * 16 + l16) * 32 + rdoff];
#pragma unroll
    for (int mi = 0; mi < 4; ++mi)
#pragma unroll
      for (int ei = 0; ei < 4; ++ei)
        acc[mi][ei] = mfma_f16(fA[mi], fB[ei], acc[mi][ei]);
    __syncthreads();
  }

  /* C/D layout: row = qd*4 + reg, col = lane&15 */
  const int third = e0 >> 9; /* 0=Q, 1=K, 2=V */
  if (third < 2) {
    u16* P = third ? Kf : Qf;
    const int ecol0 = (e0 & 511) + we;
#pragma unroll
    for (int mi = 0; mi < 4; ++mi)
#pragma unroll
      for (int ei = 0; ei < 4; ++ei)
#pragma unroll
        for (int r = 0; r < 4; ++r) {
          int row = m0 + wm + mi * 16 + qd * 4 + r;
          int col = ecol0 + ei * 16 + l16;
          P[(size_t)row * D_ + col] = f2h(acc[mi][ei][r]);
        }
  } else {
    /* V: per-wave 64x64 LDS transpose (stride 66 u16), coalesced Vt write. */
    u16* vbuf = smem + wave * 4224; /* [64][66] u16 */
#pragma unroll
    for (int mi = 0; mi < 4; ++mi)
#pragma unroll
      for (int ei = 0; ei < 4; ++ei)
#pragma unroll
        for (int r2 = 0; r2 < 2; ++r2) {
          int e_in = ei * 16 + l16;
          int m_in = mi * 16 + qd * 4 + r2 * 2;
          u32 p = (u32)f2h(acc[mi][ei][r2 * 2]) |
                  ((u32)f2h(acc[mi][ei][r2 * 2 + 1]) << 16);
          *(u32*)&vbuf[e_in * 66 + m_in] = p;
        }
    __builtin_amdgcn_s_waitcnt(0); /* drain lgkm before wave-local readback */
    const int dbase = (e0 - 1024) + we;
    const int mb = (m0 & 2047) + wm;
    const int bb = m0 >> 11;
    u16* vt = Vt + (size_t)bb * (D_ * N_);
#pragma unroll
    for (int it = 0; it < 4; ++it) {
      int e_in = it * 16 + (lane >> 2);
      int mc = lane & 3;
      u32 q0[8];
#pragma unroll
      for (int c4 = 0; c4 < 8; ++c4)
        q0[c4] = *(const u32*)&vbuf[e_in * 66 + mc * 16 + c4 * 2];
      u16* gp = vt + (size_t)(dbase + e_in) * N_ + mb + mc * 16;
      *(u32x4*)gp = (u32x4){q0[0], q0[1], q0[2], q0[3]};
      *(u32x4*)(gp + 8) = (u32x4){q0[4], q0[5], q0[6], q0[7]};
    }
  }
}

/* ---------------- MFMA sliding-window attention, fp16 single-pass ----------
 * 512 threads, 8 waves. Phase 1: wave = (jw: 3 j-tiles, kh: half of the D
 * reduction); halves summed in softmax. Phase 3: wave owns 64 d-cols.
 * Zero-pad rows (r<0): logit 0.0 in the softmax denominator, P forced 0. */
#define TQA 16
#define SA 200
#define SP 208

__global__ __launch_bounds__(512) void attn_kernel(const u16* __restrict__ Qf,
                                                   const u16* __restrict__ Kf,
                                                   const u16* __restrict__ Vt,
                                                   float* __restrict__ Out) {
  const int m0 = blockIdx.x * TQA;
  const int b = m0 >> 11;
  const int n0 = m0 & 2047;
  const int t = threadIdx.x;
  const int lane = t & 63;
  const int w = t >> 6;
  const int qd = lane >> 4;
  const int l16 = lane & 15;

  __shared__ __align__(16) float att[2][TQA][SA];
  __shared__ __align__(16) u16 pS[TQA][SP];

  const int jw = w & 3;
  const int kh = w >> 2;

  /* Phase 1: logits = Q K^T, split-K across wave pairs. */
  f32x4 acc[3];
#pragma unroll
  for (int nt = 0; nt < 3; ++nt) acc[nt] = (f32x4){0.f, 0.f, 0.f, 0.f};

  const size_t qrow = (size_t)(m0 + l16) * D_ + qd * 8;
  for (int ks = kh * 8; ks < kh * 8 + 8; ++ks) {
    u16x8 qv = *(const u16x8*)(Qf + qrow + ks * 32);
#pragma unroll
    for (int nt = 0; nt < 3; ++nt) {
      int j = (jw * 3 + nt) * 16 + l16;
      int rl = n0 - 128 + j;
      int rg = b * N_ + (rl > 0 ? rl : 0);
      u16x8 kv = *(const u16x8*)(Kf + (size_t)rg * D_ + ks * 32 + qd * 8);
      acc[nt] = mfma_f16(qv, kv, acc[nt]);
    }
  }
#pragma unroll
  for (int nt = 0; nt < 3; ++nt)
#pragma unroll
    for (int r = 0; r < 4; ++r)
      att[kh][qd * 4 + r][(jw * 3 + nt) * 16 + l16] = acc[nt][r];
  __syncthreads();

  /* Phase 2: softmax per query i over j in [i+1, i+128]; 32 thr/row. */
  {
    const int i = t >> 5;
    const int c = t & 31;
    float ev[6];
    float mx = -1e30f;
#pragma unroll
    for (int s = 0; s < 6; ++s) {
      int j = c * 6 + s;
      bool inw = (j >= i + 1) && (j <= i + 128);
      float v = -1e30f;
      if (inw) v = (n0 - 128 + j < 0) ? 0.f : att[0][i][j] + att[1][i][j];
      ev[s] = v;
      mx = fmaxf(mx, v);
    }
    mx = fmaxf(mx, __shfl_xor(mx, 1));
    mx = fmaxf(mx, __shfl_xor(mx, 2));
    mx = fmaxf(mx, __shfl_xor(mx, 4));
    mx = fmaxf(mx, __shfl_xor(mx, 8));
    mx = fmaxf(mx, __shfl_xor(mx, 16));
    float sum = 0.f;
#pragma unroll
    for (int s = 0; s < 6; ++s) {
      ev[s] = (ev[s] > -1e29f) ? __expf(ev[s] - mx) : 0.f;
      sum += ev[s];
    }
    sum += __shfl_xor(sum, 1);
    sum += __shfl_xor(sum, 2);
    sum += __shfl_xor(sum, 4);
    sum += __shfl_xor(sum, 8);
    sum += __shfl_xor(sum, 16);
    const float inv = 1.f / sum;
#pragma unroll
    for (int s = 0; s < 6; ++s) {
      int j = c * 6 + s;
      bool zv = (n0 - 128 + j) < 0;
      pS[i][j] = zv ? (u16)0 : f2h(ev[s] * inv);
    }
  }
  __syncthreads();

  /* Phase 3: Out = P V; wave w owns d-cols [w*64, w*64+64). */
  f32x4 oacc[4];
#pragma unroll
  for (int nt = 0; nt < 4; ++nt) oacc[nt] = (f32x4){0.f, 0.f, 0.f, 0.f};

  const u16* vtb = Vt + (size_t)b * (D_ * N_);
  for (int kk = 0; kk < 6; ++kk) {
    u16x8 pa = *(const u16x8*)&pS[l16][kk * 32 + qd * 8];
    const int rl = n0 - 128 + kk * 32 + qd * 8; /* may be <0: P=0 guards */
#pragma unroll
    for (int nt = 0; nt < 4; ++nt) {
      int d = w * 64 + nt * 16 + l16;
      u16x8 vv = *(const u16x8*)(vtb + (size_t)d * N_ + rl);
      oacc[nt] = mfma_f16(pa, vv, oacc[nt]);
    }
  }
#pragma unroll
  for (int nt = 0; nt < 4; ++nt)
#pragma unroll
    for (int r = 0; r < 4; ++r)
      Out[(size_t)(m0 + qd * 4 + r) * D_ + w * 64 + nt * 16 + l16] = oacc[nt][r];
}

extern "C" void kernel_launch(void* const* d_in, const int* in_sizes, int n_in,
                              void* d_out, int out_size, void* d_ws, size_t ws_size,
                              hipStream_t stream) {
  const float* x = (const float*)d_in[0];
  const float* wl = (const float*)d_in[1];
  float* out = (float*)d_out;

  u16* Xf = (u16*)d_ws;
  u16* Wf = Xf + XELEMS;
  u16* Qf = Wf + WELEMS;
  u16* Kf = Qf + QK_ELEMS;
  u16* Vt = Kf + QK_ELEMS;

  cvt_f16<<<(XELEMS + WELEMS) / 4 / 256, 256, 0, stream>>>(x, wl, Xf, Wf);
  dim3 g1(MTOT / TM, E3 / TE); /* 32 x 12 */
  qkv_gemm<<<g1, 256, 0, stream>>>(Xf, Wf, Qf, Kf, Vt);
  attn_kernel<<<MTOT / TQA, 512, 0, stream>>>(Qf, Kf, Vt, out);
}